// Round 5
// baseline (40.654 us; speedup 1.0000x reference)
//
#include <hip/hip_runtime.h>

// Length regulator (fully fused, single kernel):
//   out[b, m, :] = x[b, searchsorted_right(cum(duration[b]), m), :]  for m < mel_len[b]
//   out[b, m, :] = 0                                                 otherwise
//   mel_len[b]   = sum_t duration[b, t]   (stored as float in d_out tail)
//
// Geometry (from setup_inputs): B=32, T=512, D=384, max_len=3584.
// Fast path assumes T==512, D4==96, tot%2048==0; generic 2-kernel fallback kept.
//
// R5: replace the 9-round Hillis-Steele LDS scan (18 barriers, run redundantly
// by every block) with a wave-0-only shuffle scan (8 loads + 6 shfl + 1 barrier)
// and double per-block work (2048 float4s, 8/thread) to halve the block count.

#define LR_B 32
#define LR_T 512

typedef float f32x4 __attribute__((ext_vector_type(4)));

// ---------------------------------------------------------------------------
// Fused kernel: block = (frame-chunk, batch). 256 threads, 2048 float4s/block.
//  1. wave 0: lane l loads dur[8l..8l+7], local prefix, shfl_up scan of lane
//     totals, writes cum[512] to LDS. One barrier.
//  2. threads 0..NF-1 binary-search the block's NF (<=23) frames -> idx_s
//  3. unrolled x8 gather-copy, nontemporal streaming stores
// ---------------------------------------------------------------------------
template <int D4C>
__global__ __launch_bounds__(256) void lr_fused_kernel(
        const f32x4* __restrict__ x4,
        const int* __restrict__ dur,
        f32x4* __restrict__ out4,
        float* __restrict__ mel_out,
        int T, int max_len) {
    __shared__ int s[LR_T];
    __shared__ int idx_s[32];

    const int b  = blockIdx.y;
    const int bx = blockIdx.x;
    const int t  = threadIdx.x;

    // --- 1. wave-0 shuffle scan of duration[b, :] (512 = 64 lanes x 8) ---
    if (t < 64) {
        const int* __restrict__ db = dur + b * LR_T;
        const int4 a = *(const int4*)(db + t * 8);
        const int4 c = *(const int4*)(db + t * 8 + 4);
        const int v0 = a.x,      v1 = v0 + a.y, v2 = v1 + a.z, v3 = v2 + a.w;
        const int v4 = v3 + c.x, v5 = v4 + c.y, v6 = v5 + c.z, v7 = v6 + c.w;
        const int tot = v7;
        int pre = tot;                         // inclusive scan of lane totals
        #pragma unroll
        for (int off = 1; off < 64; off <<= 1) {
            const int u = __shfl_up(pre, off);
            if (t >= off) pre += u;
        }
        const int ex = pre - tot;              // exclusive prefix for this lane
        int4 lo4 = make_int4(ex + v0, ex + v1, ex + v2, ex + v3);
        int4 hi4 = make_int4(ex + v4, ex + v5, ex + v6, ex + v7);
        *(int4*)&s[t * 8]     = lo4;
        *(int4*)&s[t * 8 + 4] = hi4;
        if (bx == 0 && t == 63) {
            mel_out[b] = (float)pre;           // total; exact (<= 3584)
        }
    }
    __syncthreads();
    const int total = s[LR_T - 1];

    // --- 2. per-block frame index cache ---
    const int e0 = bx * 2048;                  // first float4 element of block
    const int m0 = e0 / D4C;                   // first frame touched
    const int m1 = (e0 + 2047) / D4C;          // last frame touched
    const int NF = m1 - m0 + 1;                // <= 23 for D4C==96
    if (t < NF) {
        const int m = m0 + t;
        int r = -1;
        if (m < total) {
            int lo = 0, hi = T;
            while (lo < hi) {                  // searchsorted side='right'
                const int mid = (lo + hi) >> 1;
                if (s[mid] <= m) lo = mid + 1; else hi = mid;
            }
            r = (lo < T) ? lo : (T - 1);
        }
        idx_s[t] = r;
    }
    __syncthreads();

    // --- 3. gather-copy: 8 float4s per thread, coalesced, streaming stores ---
    const f32x4* __restrict__ xb = x4 + (size_t)b * T * D4C;
    f32x4* __restrict__ ob = out4 + (size_t)b * (size_t)max_len * D4C;
    #pragma unroll
    for (int j = 0; j < 8; ++j) {
        const int e  = e0 + j * 256 + t;
        const int m  = e / D4C;                // compile-time divisor -> magic-mul
        const int d4 = e - m * D4C;
        const int id = idx_s[m - m0];          // LDS broadcast across lanes
        f32x4 v = (f32x4){0.f, 0.f, 0.f, 0.f};
        if (id >= 0) v = xb[id * D4C + d4];
        __builtin_nontemporal_store(v, &ob[e]);
    }
}

// ---------------------------------------------------------------------------
// Generic fallback path (runtime geometry), two kernels as in R2.
// ---------------------------------------------------------------------------
__global__ void lr_scan_idx_kernel(const int* __restrict__ dur,
                                   int* __restrict__ idx,
                                   float* __restrict__ mel_out,
                                   int T, int max_len) {
    __shared__ int s[LR_T];
    const int b = blockIdx.x;
    const int t = threadIdx.x;
    s[t] = dur[b * T + t];
    __syncthreads();
    #pragma unroll
    for (int off = 1; off < LR_T; off <<= 1) {
        int add = (t >= off) ? s[t - off] : 0;
        __syncthreads();
        s[t] += add;
        __syncthreads();
    }
    const int total = s[T - 1];
    if (t == 0) mel_out[b] = (float)total;
    int* __restrict__ idxb = idx + b * max_len;
    for (int m = t; m < max_len; m += LR_T) {
        int r = -1;
        if (m < total) {
            int lo = 0, hi = T;
            while (lo < hi) {
                int mid = (lo + hi) >> 1;
                if (s[mid] <= m) lo = mid + 1; else hi = mid;
            }
            r = (lo < T) ? lo : (T - 1);
        }
        idxb[m] = r;
    }
}

__global__ void lr_copy_generic(const f32x4* __restrict__ x4,
                                const int* __restrict__ idx,
                                f32x4* __restrict__ out4,
                                int T, int max_len, int D4) {
    const int b = blockIdx.y;
    const int tot = max_len * D4;
    const int e = blockIdx.x * blockDim.x + threadIdx.x;
    if (e >= tot) return;
    const int m  = e / D4;
    const int d4 = e - m * D4;
    const int id = idx[b * max_len + m];
    f32x4 v = (f32x4){0.f, 0.f, 0.f, 0.f};
    if (id >= 0) v = x4[((size_t)b * T + id) * D4 + d4];
    out4[(size_t)b * tot + e] = v;
}

extern "C" void kernel_launch(void* const* d_in, const int* in_sizes, int n_in,
                              void* d_out, int out_size, void* d_ws, size_t ws_size,
                              hipStream_t stream) {
    const float* x   = (const float*)d_in[0];
    const int*   dur = (const int*)d_in[1];

    const int B = LR_B;
    const int T = in_sizes[1] / B;                      // 512
    const int D = in_sizes[0] / in_sizes[1];            // 384
    const int max_len = (out_size / B - 1) / D;         // 3584
    const int D4 = D / 4;                               // 96
    const int tot = max_len * D4;                       // 344064 per batch

    float* out     = (float*)d_out;
    float* mel_out = out + (size_t)B * max_len * D;     // last B floats

    if (T == LR_T && D4 == 96 && (tot % 2048) == 0) {
        dim3 grid(tot / 2048, B, 1);                    // 168 x 32 = 5376 blocks
        lr_fused_kernel<96><<<grid, dim3(256, 1, 1), 0, stream>>>(
            (const f32x4*)x, dur, (f32x4*)d_out, mel_out, T, max_len);
    } else {
        int* idx = (int*)d_ws;                          // B*max_len ints
        lr_scan_idx_kernel<<<B, T, 0, stream>>>(dur, idx, mel_out, T, max_len);
        dim3 grid((tot + 255) / 256, B, 1);
        lr_copy_generic<<<grid, dim3(256, 1, 1), 0, stream>>>(
            (const f32x4*)x, idx, (f32x4*)d_out, T, max_len, D4);
    }
}

// Round 6
// 37.216 us; speedup vs baseline: 1.0924x; 1.0924x over previous
//
#include <hip/hip_runtime.h>

// Length regulator (fully fused, single kernel):
//   out[b, m, :] = x[b, searchsorted_right(cum(duration[b]), m), :]  for m < mel_len[b]
//   out[b, m, :] = 0                                                 otherwise
//   mel_len[b]   = sum_t duration[b, t]   (stored as float in d_out tail)
//
// Geometry (from setup_inputs): B=32, T=512, D=384, max_len=3584.
// Fast path assumes T==512, D4==96, gridDim.x==336; generic fallback kept.
//
// R6: exact R4 structure (best so far, 35.15us) + ONE change: bijective
// XCD-aware swizzle of blockIdx.x. Rationale: linear dispatch puts adjacent
// frame-blocks (which gather the same x rows, duration<=7 spans up to 3
// blocks) on DIFFERENT XCDs -> same x row fetched by up to 3 XCD L2s, and
// each XCD streams the whole 24MB x through its 4MB L2. Swizzle gives each
// XCD a contiguous 42-block chunk per batch -> x-row reuse stays XCD-local.
// (R5 lesson: the all-thread scan prologue is NOT the bottleneck — wave-0-only
// scan + 8-deep unroll regressed 35->41us; reverted.)

#define LR_B 32
#define LR_T 512

typedef float f32x4 __attribute__((ext_vector_type(4)));

// ---------------------------------------------------------------------------
// Fused kernel: block = (frame-chunk, batch). 256 threads, 1024 float4s/block.
//  1. load 512 durations -> LDS, Hillis-Steele inclusive scan (2 elems/thread)
//  2. threads 0..NF-1 binary-search the block's NF (<=12) frames -> idx_s
//  3. unrolled x4 gather-copy, nontemporal streaming stores
// ---------------------------------------------------------------------------
template <int D4C>
__global__ __launch_bounds__(256) void lr_fused_kernel(
        const f32x4* __restrict__ x4,
        const int* __restrict__ dur,
        f32x4* __restrict__ out4,
        float* __restrict__ mel_out,
        int T, int max_len) {
    __shared__ int s[LR_T];
    __shared__ int idx_s[16];

    const int b  = blockIdx.y;
    const int t  = threadIdx.x;

    // XCD swizzle: hardware round-robins linear workgroup id over 8 XCDs;
    // gridDim.x==336 (==0 mod 8) so physical XCD = blockIdx.x % 8. Remap so
    // XCD k owns contiguous logical chunk [k*42, (k+1)*42) of every batch.
    const int bxp = blockIdx.x;
    const int bx  = (gridDim.x == 336) ? (bxp % 8) * 42 + (bxp >> 3) : bxp;

    // --- 1. scan of duration[b, :] (512 elems, 256 threads, 2 per thread) ---
    const int* __restrict__ db = dur + b * LR_T;
    s[t]       = db[t];
    s[t + 256] = db[t + 256];
    __syncthreads();
    #pragma unroll
    for (int off = 1; off < LR_T; off <<= 1) {
        const int p1 = t + 256;
        const int a0 = (t >= off) ? s[t - off] : 0;
        const int a1 = s[p1 - off];            // p1 >= 256 >= off always
        __syncthreads();
        s[t]  += a0;
        s[p1] += a1;
        __syncthreads();
    }
    const int total = s[LR_T - 1];

    if (bx == 0 && t == 0) {
        mel_out[b] = (float)total;             // exact: total <= 3584 << 2^24
    }

    // --- 2. per-block frame index cache ---
    const int e0 = bx * 1024;                  // first float4 element of block
    const int m0 = e0 / D4C;                   // first frame touched
    const int m1 = (e0 + 1023) / D4C;          // last frame touched
    const int NF = m1 - m0 + 1;                // <= 12 for D4C==96
    if (t < NF) {
        const int m = m0 + t;
        int r = -1;
        if (m < total) {
            int lo = 0, hi = T;
            while (lo < hi) {                  // searchsorted side='right'
                const int mid = (lo + hi) >> 1;
                if (s[mid] <= m) lo = mid + 1; else hi = mid;
            }
            r = (lo < T) ? lo : (T - 1);
        }
        idx_s[t] = r;
    }
    __syncthreads();

    // --- 3. gather-copy: 4 float4s per thread, coalesced, streaming stores ---
    const f32x4* __restrict__ xb = x4 + (size_t)b * T * D4C;
    f32x4* __restrict__ ob = out4 + (size_t)b * (size_t)max_len * D4C;
    #pragma unroll
    for (int j = 0; j < 4; ++j) {
        const int e  = e0 + j * 256 + t;
        const int m  = e / D4C;                // compile-time divisor -> magic-mul
        const int d4 = e - m * D4C;
        const int id = idx_s[m - m0];          // LDS broadcast across lanes
        f32x4 v = (f32x4){0.f, 0.f, 0.f, 0.f};
        if (id >= 0) v = xb[id * D4C + d4];
        __builtin_nontemporal_store(v, &ob[e]);
    }
}

// ---------------------------------------------------------------------------
// Generic fallback path (runtime geometry), two kernels as in R2.
// ---------------------------------------------------------------------------
__global__ void lr_scan_idx_kernel(const int* __restrict__ dur,
                                   int* __restrict__ idx,
                                   float* __restrict__ mel_out,
                                   int T, int max_len) {
    __shared__ int s[LR_T];
    const int b = blockIdx.x;
    const int t = threadIdx.x;
    s[t] = dur[b * T + t];
    __syncthreads();
    #pragma unroll
    for (int off = 1; off < LR_T; off <<= 1) {
        int add = (t >= off) ? s[t - off] : 0;
        __syncthreads();
        s[t] += add;
        __syncthreads();
    }
    const int total = s[T - 1];
    if (t == 0) mel_out[b] = (float)total;
    int* __restrict__ idxb = idx + b * max_len;
    for (int m = t; m < max_len; m += LR_T) {
        int r = -1;
        if (m < total) {
            int lo = 0, hi = T;
            while (lo < hi) {
                int mid = (lo + hi) >> 1;
                if (s[mid] <= m) lo = mid + 1; else hi = mid;
            }
            r = (lo < T) ? lo : (T - 1);
        }
        idxb[m] = r;
    }
}

__global__ void lr_copy_generic(const f32x4* __restrict__ x4,
                                const int* __restrict__ idx,
                                f32x4* __restrict__ out4,
                                int T, int max_len, int D4) {
    const int b = blockIdx.y;
    const int tot = max_len * D4;
    const int e = blockIdx.x * blockDim.x + threadIdx.x;
    if (e >= tot) return;
    const int m  = e / D4;
    const int d4 = e - m * D4;
    const int id = idx[b * max_len + m];
    f32x4 v = (f32x4){0.f, 0.f, 0.f, 0.f};
    if (id >= 0) v = x4[((size_t)b * T + id) * D4 + d4];
    out4[(size_t)b * tot + e] = v;
}

extern "C" void kernel_launch(void* const* d_in, const int* in_sizes, int n_in,
                              void* d_out, int out_size, void* d_ws, size_t ws_size,
                              hipStream_t stream) {
    const float* x   = (const float*)d_in[0];
    const int*   dur = (const int*)d_in[1];

    const int B = LR_B;
    const int T = in_sizes[1] / B;                      // 512
    const int D = in_sizes[0] / in_sizes[1];            // 384
    const int max_len = (out_size / B - 1) / D;         // 3584
    const int D4 = D / 4;                               // 96
    const int tot = max_len * D4;                       // 344064 per batch

    float* out     = (float*)d_out;
    float* mel_out = out + (size_t)B * max_len * D;     // last B floats

    if (T == LR_T && D4 == 96 && (tot % 1024) == 0) {
        dim3 grid(tot / 1024, B, 1);                    // 336 x 32 = 10752 blocks
        lr_fused_kernel<96><<<grid, dim3(256, 1, 1), 0, stream>>>(
            (const f32x4*)x, dur, (f32x4*)d_out, mel_out, T, max_len);
    } else {
        int* idx = (int*)d_ws;                          // B*max_len ints
        lr_scan_idx_kernel<<<B, T, 0, stream>>>(dur, idx, mel_out, T, max_len);
        dim3 grid((tot + 255) / 256, B, 1);
        lr_copy_generic<<<grid, dim3(256, 1, 1), 0, stream>>>(
            (const f32x4*)x, idx, (f32x4*)d_out, T, max_len, D4);
    }
}